// Round 16
// baseline (8102.528 us; speedup 1.0000x reference)
//
#include <hip/hip_runtime.h>
#include <math.h>

#define T_STEPS 2048
#define BATCH   32
#define IN_DIM  512
#define H_DIM   512
#define G4      2048
#define NWG     16       // scan workgroups
#define NXW     512      // xw producer workgroups
#define NTHR    512
#define GLS     132      // gates LDS row stride (floats), padded

typedef __attribute__((ext_vector_type(8))) short short8;
typedef __attribute__((ext_vector_type(4))) float f32x4;
typedef __attribute__((ext_vector_type(2))) float f32x2;
typedef __attribute__((ext_vector_type(4))) unsigned u32x4;

__device__ inline unsigned short f2bf(float f) {
    unsigned u = __builtin_bit_cast(unsigned, f);
    unsigned r = (u + 0x7FFFu + ((u >> 16) & 1u)) >> 16;
    return (unsigned short)r;
}
__device__ inline unsigned pack2(float a, float b) {
    return (unsigned)f2bf(a) | ((unsigned)f2bf(b) << 16);
}
__device__ inline float h2f(unsigned u) {
    _Float16 h = __builtin_bit_cast(_Float16, (unsigned short)(u & 0xFFFFu));
    return (float)h;
}
// fast transcendentals: v_exp_f32 / v_rcp_f32 (~2 ulp; bf16 noise dominates)
__device__ inline float fsigm(float x) {
    return __builtin_amdgcn_rcpf(1.f + __expf(-x));
}
__device__ inline float ftanh(float x) {
    return 1.f - 2.f * __builtin_amdgcn_rcpf(__expf(2.f * x) + 1.f);
}
__device__ inline float sigm(float v) { return 1.f / (1.f + expf(-v)); }  // fallback

// 4 parallel IC-coherent 16B loads + drain (R4-proven)
__device__ inline void ld4x_ic(const void* p0, const void* p1,
                               const void* p2, const void* p3,
                               u32x4& v0, u32x4& v1, u32x4& v2, u32x4& v3) {
    asm volatile(
        "global_load_dwordx4 %0, %4, off sc1\n\t"
        "global_load_dwordx4 %1, %5, off sc1\n\t"
        "global_load_dwordx4 %2, %6, off sc1\n\t"
        "global_load_dwordx4 %3, %7, off sc1\n\t"
        "s_waitcnt vmcnt(0)"
        : "=&v"(v0), "=&v"(v1), "=&v"(v2), "=&v"(v3)
        : "v"(p0), "v"(p1), "v"(p2), "v"(p3) : "memory");
}

// ---------------------------------------------------------------------------
// W [1024][2048] fp32 -> Wt [2048][1024] bf16 (transposed; k<512 = x-part)
// ---------------------------------------------------------------------------
__global__ __launch_bounds__(256) void wt_kernel(const float* __restrict__ W,
                                                 unsigned short* __restrict__ Wt) {
    __shared__ unsigned short tile[32][33];
    const int n0 = blockIdx.x << 5, k0 = blockIdx.y << 5;
    const int tx = threadIdx.x & 31, ty = threadIdx.x >> 5;
    #pragma unroll
    for (int r = 0; r < 32; r += 8)
        tile[ty + r][tx] = f2bf(W[(size_t)(k0 + ty + r) * G4 + n0 + tx]);
    __syncthreads();
    #pragma unroll
    for (int r = 0; r < 32; r += 8)
        Wt[(size_t)(n0 + ty + r) * 1024 + k0 + tx] = tile[tx][ty + r];
}

__global__ void init_h(const float* __restrict__ h0, unsigned short* __restrict__ hb) {
    int i = blockIdx.x * 256 + threadIdx.x;   // 16384 total
    hb[i] = f2bf(h0[i]);
}

// ---------------------------------------------------------------------------
// Fused kernel: blocks 0..15 = persistent scan (prio 1); 16..527 = producers.
//
// Producers (R14-proven protocol; FIXED store pattern): 512-thr block = two
// 256-thr tile engines. 32 chunk-ordered iterations (chunk = 64 steps).
// Epilogue: acc -> padded LDS tile [64][72] fp16 -> 2x dwordx4 sc1 per thread
// (full 128B lines per 4 threads; replaces R14's 16x 2B scalar sc1 stores
// that poisoned the IC). Then vmcnt(0) -> sync -> chunkcnt[iter] += 2
// (target 1024) — byte-identical publication protocol to R14.
//
// Scan: R15's proven body (per-thread producer polling) + R14's proven
// chunk gating + sc1 pre loads + s_setprio(1) (issue preference on CUs
// shared with producers during the ~750us production window).
// ---------------------------------------------------------------------------
__global__ __launch_bounds__(NTHR, 1) void lstm_fused(
        const unsigned short* __restrict__ Wt,   // [2048][1024], h-part at k+512
        const float* __restrict__ x,             // [2048][32][512] fp32
        const float* __restrict__ bias,          // [2048]
        unsigned short* __restrict__ pre16u,     // [65536][2048] fp16 bits (ws)
        const float* __restrict__ c0,            // [32][512]
        unsigned short* __restrict__ hbuf,       // [2][32][512] bf16, [0] init'd
        float* __restrict__ outs,                // [2048][32][512]
        float* __restrict__ hf, float* __restrict__ cf,
        unsigned* __restrict__ sync_area) {      // [0..255] WG flags; [512..543] chunkcnt
    __shared__ char LDS_[49664];
    const int bid = blockIdx.x;
    const int tid = threadIdx.x;
    unsigned* flags    = sync_area;
    unsigned* chunkcnt = sync_area + 512;

    if (bid >= NWG) {
        // ================= xw producer =================
        const int xid  = bid - NWG;          // 0..511
        const int half = tid >> 8;           // two 256-thr engines
        const int t256 = tid & 255;
        unsigned short (*As)[40] = (unsigned short(*)[40])(LDS_ + half * 10240);
        unsigned short (*Bs)[40] = (unsigned short(*)[40])(LDS_ + half * 10240 + 5120);
        unsigned short (*ep)[72] = (unsigned short(*)[72])(LDS_ + 20480 + half * 9216);
        const int ht  = xid * 2 + half;      // half-tile id 0..1023
        const int bn  = ht & 31, bml = ht >> 5;
        const int n0  = bn << 6;
        const int w2  = t256 >> 6, l2 = t256 & 63;
        const int srow = t256 >> 2, sseg = (t256 & 3) << 3;
        const int arow = (w2 << 4) + (l2 & 15);
        const int kb   = (l2 >> 4) << 3;

        for (int iter = 0; iter < 32; ++iter) {      // iteration i == chunk i
            const int m0 = ((iter << 5) + bml) << 6;
            f32x4 acc[4] = {};
            for (int kc = 0; kc < 16; ++kc) {
                const float* xs = x + (size_t)(m0 + srow) * IN_DIM + kc * 32 + sseg;
                float4 xa = *(const float4*)xs;
                float4 xb2 = *(const float4*)(xs + 4);
                int4 av;
                av.x = pack2(xa.x, xa.y);  av.y = pack2(xa.z, xa.w);
                av.z = pack2(xb2.x, xb2.y); av.w = pack2(xb2.z, xb2.w);
                *(int4*)&As[srow][sseg] = av;
                *(int4*)&Bs[srow][sseg] =
                    *(const int4*)(Wt + (size_t)(n0 + srow) * 1024 + kc * 32 + sseg);
                __syncthreads();
                short8 af = *(const short8*)&As[arow][kb];
                #pragma unroll
                for (int n = 0; n < 4; ++n) {
                    short8 bf = *(const short8*)&Bs[(n << 4) + (l2 & 15)][kb];
                    acc[n] = __builtin_amdgcn_mfma_f32_16x16x32_bf16(af, bf, acc[n], 0, 0, 0);
                }
                __syncthreads();
            }
            // epilogue: acc -> padded LDS tile (bias folded), then coalesced
            // sc1 stores (2x dwordx4 per thread, 128B lines per 4 threads)
            #pragma unroll
            for (int n = 0; n < 4; ++n) {
                const int col = (n << 4) + (l2 & 15);
                const float bb = bias[n0 + col];
                #pragma unroll
                for (int ri = 0; ri < 4; ++ri) {
                    const int row = (w2 << 4) + ((l2 >> 4) << 2) + ri;
                    ep[row][col] = __builtin_bit_cast(unsigned short,
                                                      (_Float16)(acc[n][ri] + bb));
                }
            }
            __syncthreads();                         // both halves' tiles done
            {
                const int row = t256 >> 2, seg = (t256 & 3) << 4;  // shorts
                const unsigned short* src = &ep[row][seg];
                u32x4 q0 = *(const u32x4*)(src);
                u32x4 q1 = *(const u32x4*)(src + 8);
                unsigned short* pd = pre16u + (size_t)(m0 + row) * G4 + n0 + seg;
                asm volatile("global_store_dwordx4 %0, %1, off sc1\n\t"
                             "global_store_dwordx4 %2, %3, off sc1"
                             :: "v"(pd), "v"(q0), "v"(pd + 8), "v"(q1) : "memory");
            }
            asm volatile("s_waitcnt vmcnt(0)" ::: "memory");
            __syncthreads();                         // all stores drained
            if (tid == 0) atomicAdd(chunkcnt + iter, 2u);
        }
        return;
    }

    // ================= persistent scan =================
    const int g = bid;
    const int w = tid >> 6, l = tid & 63;
    char* Hl = LDS_;                     // h: 32 rows x 1KB, swizzled
    float* Gl = (float*)(LDS_ + 32768);  // gates: 16.9KB

    // --- W_h fragments: wave w -> global gate cols gc (16 cols/wave)
    const int gc = ((w >> 1) << 9) + (g << 5) + ((w & 1) << 4) + (l & 15);
    const int ksub = (l >> 4) << 3;
    short8 wfh[16];
    #pragma unroll
    for (int kc = 0; kc < 16; ++kc)
        wfh[kc] = *(const short8*)(Wt + (size_t)gc * 1024 + 512 + kc * 32 + ksub);

    // --- update-phase mapping: thread -> (b, even col pair)
    const int b   = tid >> 4;
    const int hcp = (tid & 15) << 1;
    const int col = (g << 5) + hcp;
    float2 cv = *(const float2*)(c0 + (b << 9) + col);

    const int arow0 = l & 15, arow1 = (l & 15) + 16;
    const int kbyte = (l >> 4) << 4;
    const int swz0 = (arow0 & 7) << 4, swz1 = (arow1 & 7) << 4;
    const int lcw = (w << 4) + (l & 15);

    // --- stage h(0) -> Hl (IC loads; hbuf[0] from init_h, prior dispatch)
    {
        const unsigned short* hp0 = hbuf + (w << 9) + (l << 3);
        u32x4 v0, v1, v2, v3;
        ld4x_ic(hp0, hp0 + 4096, hp0 + 8192, hp0 + 12288, v0, v1, v2, v3);
        char* hd = Hl + w * 1024 + ((l << 4) ^ (w << 4));
        *(u32x4*)hd = v0; *(u32x4*)(hd + 8192) = v1;
        *(u32x4*)(hd + 16384) = v2; *(u32x4*)(hd + 24576) = v3;
    }
    __syncthreads();
    __builtin_amdgcn_s_setprio(1);       // scan waves win issue arbitration

    // --- wait for pre chunk 0, then initial prefetch (sc1)
    for (;;) {
        unsigned vb;
        asm volatile("global_load_dword %0, %1, off sc1\n\ts_waitcnt vmcnt(0)"
                     : "=v"(vb) : "v"(chunkcnt) : "memory");
        if (vb >= 1024u) break;
        __builtin_amdgcn_s_sleep(4);
    }
    unsigned puf, pui, pug, puo;
    {
        const unsigned* pp = (const unsigned*)(pre16u + ((size_t)b << 11) + col);
        asm volatile("global_load_dword %0, %4, off sc1\n\t"
                     "global_load_dword %1, %4, off offset:1024 sc1\n\t"
                     "global_load_dword %2, %4, off offset:2048 sc1\n\t"
                     "global_load_dword %3, %4, off offset:3072 sc1"
                     : "=&v"(puf), "=&v"(pui), "=&v"(pug), "=&v"(puo)
                     : "v"(pp) : "memory");
    }

    for (int gt = 0; gt < T_STEPS; ++gt) {
        // A. MFMA: h[32,512] @ Wh[512,16/wave] -> gates
        f32x4 acc0 = {0.f, 0.f, 0.f, 0.f}, acc1 = {0.f, 0.f, 0.f, 0.f};
        #pragma unroll
        for (int kc = 0; kc < 16; ++kc) {
            const int kb2 = kc * 64 + kbyte;
            short8 ha0 = *(const short8*)(Hl + arow0 * 1024 + (kb2 ^ swz0));
            short8 ha1 = *(const short8*)(Hl + arow1 * 1024 + (kb2 ^ swz1));
            acc0 = __builtin_amdgcn_mfma_f32_16x16x32_bf16(ha0, wfh[kc], acc0, 0, 0, 0);
            acc1 = __builtin_amdgcn_mfma_f32_16x16x32_bf16(ha1, wfh[kc], acc1, 0, 0, 0);
        }

        // B. gates -> Gl
        #pragma unroll
        for (int ri = 0; ri < 4; ++ri) {
            const int br = ((l >> 4) << 2) + ri;
            Gl[br * GLS + lcw] = acc0[ri];
            Gl[(br + 16) * GLS + lcw] = acc1[ri];
        }
        __syncthreads();                 // (sync 1) gates visible

        // C. pre loads (issued last iter) now required
        asm volatile("s_waitcnt vmcnt(0)" ::: "memory");
        __builtin_amdgcn_sched_barrier(0);

        // D. elementwise update (fast transcendentals, fp16 pre unpack)
        const float* grow = Gl + b * GLS + hcp;
        const float2 g_f = *(const float2*)(grow);
        const float2 g_i = *(const float2*)(grow + 32);
        const float2 g_g = *(const float2*)(grow + 64);
        const float2 g_o = *(const float2*)(grow + 96);
        const float f0 = fsigm(g_f.x + h2f(puf)), f1 = fsigm(g_f.y + h2f(puf >> 16));
        const float i0 = fsigm(g_i.x + h2f(pui)), i1 = fsigm(g_i.y + h2f(pui >> 16));
        const float g0 = ftanh(g_g.x + h2f(pug)), g1 = ftanh(g_g.y + h2f(pug >> 16));
        const float o0 = fsigm(g_o.x + h2f(puo)), o1 = fsigm(g_o.y + h2f(puo >> 16));
        cv.x = f0 * cv.x + i0 * g0;
        cv.y = f1 * cv.y + i1 * g1;
        const float hn0 = o0 * ftanh(cv.x);
        const float hn1 = o1 * ftanh(cv.y);

        // E. stores: h for next step FIRST (sc1), then outs (plain)
        {
            unsigned* hdst = (unsigned*)hbuf + (((gt + 1) & 1) << 13) + (b << 8) + (col >> 1);
            const unsigned pk = pack2(hn0, hn1);
            asm volatile("global_store_dword %0, %1, off sc1" :: "v"(hdst), "v"(pk) : "memory");
            float* optr = outs + ((size_t)gt << 14) + (b << 9) + col;
            f32x2 ov; ov.x = hn0; ov.y = hn1;
            asm volatile("global_store_dwordx2 %0, %1, off" :: "v"(optr), "v"(ov) : "memory");
        }
        if (gt == T_STEPS - 1) {
            *(float2*)(hf + (b << 9) + col) = make_float2(hn0, hn1);
            *(float2*)(cf + (b << 9) + col) = make_float2(cv.x, cv.y);
            break;                              // no final barrier needed
        }

        // F. chunk-ready gate for next prefetch (once per 64 steps)
        if (((gt + 1) & 63) == 0) {
            const unsigned* cc = chunkcnt + ((gt + 1) >> 6);
            for (;;) {
                unsigned vb;
                asm volatile("global_load_dword %0, %1, off sc1\n\ts_waitcnt vmcnt(0)"
                             : "=v"(vb) : "v"(cc) : "memory");
                if (vb >= 1024u) break;
                __builtin_amdgcn_s_sleep(2);
            }
        }

        // G. issue pre prefetch for gt+1 (sc1)
        {
            const unsigned* pp = (const unsigned*)
                (pre16u + (((size_t)(gt + 1) << 5) + b) * 2048 + col);
            asm volatile("global_load_dword %0, %4, off sc1\n\t"
                         "global_load_dword %1, %4, off offset:1024 sc1\n\t"
                         "global_load_dword %2, %4, off offset:2048 sc1\n\t"
                         "global_load_dword %3, %4, off offset:3072 sc1"
                         : "=&v"(puf), "=&v"(pui), "=&v"(pug), "=&v"(puo)
                         : "v"(pp) : "memory");
        }
        // H. drain the h store (oldest; outs store + 4 loads stay in flight)
        asm volatile("s_waitcnt vmcnt(5)" ::: "memory");

        // I. arrival: all waves' h stores drained -> tid0 publishes step done
        __syncthreads();                 // (sync 2)
        if (tid == 0)
            atomicAdd(flags + (g << 4), 1u);    // slot value = steps done

        // J. per-thread producer poll + immediate staging (R15-proven):
        //    thread (w,l) needs cols [l*8,l*8+8) -> producer WG l>>2 only.
        {
            unsigned* slot = flags + ((l >> 2) << 4);
            const unsigned tgt = (unsigned)(gt + 1);
            for (;;) {
                unsigned vb;
                asm volatile("global_load_dword %0, %1, off sc1\n\ts_waitcnt vmcnt(0)"
                             : "=v"(vb) : "v"(slot) : "memory");
                if (vb >= tgt) break;
            }
            const unsigned short* hsrc = hbuf + (((gt + 1) & 1) << 14) + (w << 9) + (l << 3);
            u32x4 v0, v1, v2, v3;
            ld4x_ic(hsrc, hsrc + 4096, hsrc + 8192, hsrc + 12288, v0, v1, v2, v3);
            char* hd = Hl + w * 1024 + ((l << 4) ^ (w << 4));
            *(u32x4*)hd = v0; *(u32x4*)(hd + 8192) = v1;
            *(u32x4*)(hd + 16384) = v2; *(u32x4*)(hd + 24576) = v3;
        }
        __syncthreads();                 // (sync 3) Hl ready
    }
}

// ---------------------------------------------------------------------------
// Minimal fallback (tiny ws): 2048 step launches, fp32, x folded in.
// ---------------------------------------------------------------------------
__global__ __launch_bounds__(256) void lstm_step(const float* __restrict__ x_t,
                                                 const float* __restrict__ h_prev,
                                                 const float* __restrict__ W,
                                                 const float* __restrict__ bias,
                                                 const float* __restrict__ c_in,
                                                 float* __restrict__ c_out,
                                                 float* __restrict__ h_out,
                                                 float* __restrict__ hf,
                                                 float* __restrict__ cf, int last) {
    const int tid = threadIdx.x;
    const int hcc = tid & 7, b = tid >> 3;
    const int col = blockIdx.x * 8 + hcc;
    float a0 = bias[col], a1 = bias[col + 512], a2 = bias[col + 1024], a3 = bias[col + 1536];
    const float* xr = x_t + (size_t)b * IN_DIM;
    const float* hr = h_prev + (size_t)b * H_DIM;
    for (int k = 0; k < IN_DIM; ++k) {
        const float v = xr[k];
        const float* wk = &W[(size_t)k * G4 + col];
        a0 += v * wk[0]; a1 += v * wk[512]; a2 += v * wk[1024]; a3 += v * wk[1536];
    }
    for (int k = 0; k < H_DIM; ++k) {
        const float v = hr[k];
        const float* wk = &W[(size_t)(512 + k) * G4 + col];
        a0 += v * wk[0]; a1 += v * wk[512]; a2 += v * wk[1024]; a3 += v * wk[1536];
    }
    const float cn = sigm(a0) * c_in[(size_t)b * H_DIM + col] + sigm(a1) * tanhf(a2);
    const float hn = sigm(a3) * tanhf(cn);
    c_out[(size_t)b * H_DIM + col] = cn;
    h_out[(size_t)b * H_DIM + col] = hn;
    if (last) { hf[(size_t)b * H_DIM + col] = hn; cf[(size_t)b * H_DIM + col] = cn; }
}

extern "C" void kernel_launch(void* const* d_in, const int* in_sizes, int n_in,
                              void* d_out, int out_size, void* d_ws, size_t ws_size,
                              hipStream_t stream) {
    const float* x    = (const float*)d_in[0];
    const float* h0   = (const float*)d_in[1];
    const float* c0   = (const float*)d_in[2];
    const float* W    = (const float*)d_in[3];
    const float* bias = (const float*)d_in[4];

    float* outs = (float*)d_out;
    float* hf   = outs + (size_t)T_STEPS * BATCH * H_DIM;
    float* cf   = hf + BATCH * H_DIM;

    // pre16 256 MiB + Wt 4 MiB + hbuf 64 KiB + sync 4 KiB = 272.7 MB
    // (< proven-available 536.9 MB)
    const size_t OFF_WT = 268435456ull;
    const size_t OFF_HB = OFF_WT + 4194304ull;
    const size_t OFF_SY = OFF_HB + 65536ull;
    const size_t NEED   = OFF_SY + 4096ull;

    if (ws_size >= NEED) {
        unsigned short* pre16u = (unsigned short*)d_ws;
        unsigned short* Wt     = (unsigned short*)((char*)d_ws + OFF_WT);
        unsigned short* hb     = (unsigned short*)((char*)d_ws + OFF_HB);
        unsigned* sync_a       = (unsigned*)((char*)d_ws + OFF_SY);

        hipMemsetAsync(sync_a, 0, 4096, stream);
        wt_kernel<<<dim3(64, 32), 256, 0, stream>>>(W, Wt);
        init_h<<<64, 256, 0, stream>>>(h0, hb);
        lstm_fused<<<NWG + NXW, NTHR, 0, stream>>>(Wt, x, bias, pre16u, c0, hb,
                                                   outs, hf, cf, sync_a);
    } else {
        float* c_ws = (float*)d_ws;
        for (int t = 0; t < T_STEPS; ++t) {
            const float* hp = t ? outs + (size_t)(t - 1) * BATCH * H_DIM : h0;
            const float* ci = t ? c_ws : c0;
            lstm_step<<<64, 256, 0, stream>>>(x + (size_t)t * BATCH * IN_DIM,
                                              hp, W, bias, ci, c_ws,
                                              outs + (size_t)t * BATCH * H_DIM,
                                              hf, cf, (t == T_STEPS - 1) ? 1 : 0);
        }
    }
}

// Round 17
// 7312.822 us; speedup vs baseline: 1.1080x; 1.1080x over previous
//
#include <hip/hip_runtime.h>
#include <math.h>

#define T_STEPS 2048
#define BATCH   32
#define IN_DIM  512
#define H_DIM   512
#define G4      2048
#define NWG     16
#define NTHR    512
#define GLS     132      // gates LDS row stride (floats), padded

typedef __attribute__((ext_vector_type(8))) short short8;
typedef __attribute__((ext_vector_type(4))) float f32x4;
typedef __attribute__((ext_vector_type(2))) float f32x2;
typedef __attribute__((ext_vector_type(4))) unsigned u32x4;

__device__ inline unsigned short f2bf(float f) {
    unsigned u = __builtin_bit_cast(unsigned, f);
    unsigned r = (u + 0x7FFFu + ((u >> 16) & 1u)) >> 16;
    return (unsigned short)r;
}
__device__ inline unsigned pack2(float a, float b) {
    return (unsigned)f2bf(a) | ((unsigned)f2bf(b) << 16);
}
__device__ inline float h2f(unsigned u) {
    _Float16 h = __builtin_bit_cast(_Float16, (unsigned short)(u & 0xFFFFu));
    return (float)h;
}
// fast transcendentals: v_exp_f32 / v_rcp_f32 (~2 ulp; bf16 noise dominates)
__device__ inline float fsigm(float x) {
    return __builtin_amdgcn_rcpf(1.f + __expf(-x));
}
__device__ inline float ftanh(float x) {
    return 1.f - 2.f * __builtin_amdgcn_rcpf(__expf(2.f * x) + 1.f);
}
__device__ inline float sigm(float v) { return 1.f / (1.f + expf(-v)); }  // fallback

// 4 parallel IC-coherent 16B loads + drain (R4-proven)
__device__ inline void ld4x_ic(const void* p0, const void* p1,
                               const void* p2, const void* p3,
                               u32x4& v0, u32x4& v1, u32x4& v2, u32x4& v3) {
    asm volatile(
        "global_load_dwordx4 %0, %4, off sc1\n\t"
        "global_load_dwordx4 %1, %5, off sc1\n\t"
        "global_load_dwordx4 %2, %6, off sc1\n\t"
        "global_load_dwordx4 %3, %7, off sc1\n\t"
        "s_waitcnt vmcnt(0)"
        : "=&v"(v0), "=&v"(v1), "=&v"(v2), "=&v"(v3)
        : "v"(p0), "v"(p1), "v"(p2), "v"(p3) : "memory");
}

// ---------------------------------------------------------------------------
// W [1024][2048] fp32 -> Wt [2048][1024] bf16 (transposed; k<512 = x-part)
// ---------------------------------------------------------------------------
__global__ __launch_bounds__(256) void wt_kernel(const float* __restrict__ W,
                                                 unsigned short* __restrict__ Wt) {
    __shared__ unsigned short tile[32][33];
    const int n0 = blockIdx.x << 5, k0 = blockIdx.y << 5;
    const int tx = threadIdx.x & 31, ty = threadIdx.x >> 5;
    #pragma unroll
    for (int r = 0; r < 32; r += 8)
        tile[ty + r][tx] = f2bf(W[(size_t)(k0 + ty + r) * G4 + n0 + tx]);
    __syncthreads();
    #pragma unroll
    for (int r = 0; r < 32; r += 8)
        Wt[(size_t)(n0 + ty + r) * 1024 + k0 + tx] = tile[tx][ty + r];
}

__global__ void init_h(const float* __restrict__ h0, unsigned short* __restrict__ hb) {
    int i = blockIdx.x * 256 + threadIdx.x;   // 16384 total
    hb[i] = f2bf(h0[i]);
}

// ---------------------------------------------------------------------------
// Phase 1 (full T): pre16[m][col] = fp16(x[m][:] @ W[0:512][col] + bias[col]).
// M=65536, N=2048, K=512. BM=BN=64, BK=32, 4 waves. (R13-proven, plain stores)
// ---------------------------------------------------------------------------
__global__ __launch_bounds__(256) void xw_mfma(const float* __restrict__ x,
                                               const unsigned short* __restrict__ Wt,
                                               const float* __restrict__ bias,
                                               _Float16* __restrict__ pre16) {
    __shared__ unsigned short As[64][40];   // row stride 80B (16B-aligned)
    __shared__ unsigned short Bs[64][40];
    const int tid = threadIdx.x;
    const int w = tid >> 6, l = tid & 63;
    const int m0 = blockIdx.y << 6, n0 = blockIdx.x << 6;
    const int srow = tid >> 2, sseg = (tid & 3) << 3;
    const int arow = (w << 4) + (l & 15);
    const int kb = (l >> 4) << 3;
    f32x4 acc[4] = {};

    for (int kc = 0; kc < 16; ++kc) {
        const float* xs = x + (size_t)(m0 + srow) * IN_DIM + kc * 32 + sseg;
        float4 xa = *(const float4*)xs;
        float4 xb2 = *(const float4*)(xs + 4);
        int4 av;
        av.x = pack2(xa.x, xa.y);  av.y = pack2(xa.z, xa.w);
        av.z = pack2(xb2.x, xb2.y); av.w = pack2(xb2.z, xb2.w);
        *(int4*)&As[srow][sseg] = av;
        *(int4*)&Bs[srow][sseg] = *(const int4*)(Wt + (size_t)(n0 + srow) * 1024 + kc * 32 + sseg);
        __syncthreads();
        short8 af = *(const short8*)&As[arow][kb];
        #pragma unroll
        for (int n = 0; n < 4; ++n) {
            short8 bf = *(const short8*)&Bs[(n << 4) + (l & 15)][kb];
            acc[n] = __builtin_amdgcn_mfma_f32_16x16x32_bf16(af, bf, acc[n], 0, 0, 0);
        }
        __syncthreads();
    }
    #pragma unroll
    for (int n = 0; n < 4; ++n) {
        const int col = n0 + (n << 4) + (l & 15);
        const float bb = bias[col];
        #pragma unroll
        for (int ri = 0; ri < 4; ++ri) {
            const int row = m0 + (w << 4) + ((l >> 4) << 2) + ri;
            pre16[(size_t)row * G4 + col] = (_Float16)(acc[n][ri] + bb);
        }
    }
}

// ---------------------------------------------------------------------------
// Persistent scan, SINGLE dispatch (R13-proven structure + R15's per-thread
// producer polling). Staging thread (w,l) needs h-cols [l*8,l*8+8), produced
// entirely by WG l>>2, so it polls THAT flag and loads immediately; trailing
// __syncthreads restores full-barrier semantics (l>>2 spans all 16 WGs).
// ---------------------------------------------------------------------------
__global__ __launch_bounds__(NTHR, 1) void lstm_scan(
        const unsigned short* __restrict__ Wt,     // [2048][1024], h-part at k+512
        const unsigned short* __restrict__ pre16u, // [65536][2048] fp16, bias incl.
        const float* __restrict__ c0,              // [32][512]
        unsigned short* __restrict__ hbuf,         // [2][32][512] bf16, [0] init'd
        float* __restrict__ outs,                  // [2048][32][512]
        float* __restrict__ hf, float* __restrict__ cf,
        unsigned int* __restrict__ flags) {        // 16 slots, 64B apart
    __shared__ char Hl[32768];        // h: 32 rows x 1KB, swizzled
    __shared__ float Gl[32 * GLS];    // gates: separate region (16.9KB)

    const int g = blockIdx.x;
    const int tid = threadIdx.x;
    const int w = tid >> 6, l = tid & 63;

    // --- W_h fragments: wave w -> global gate cols gc (16 cols/wave)
    const int gc = ((w >> 1) << 9) + (g << 5) + ((w & 1) << 4) + (l & 15);
    const int ksub = (l >> 4) << 3;
    short8 wfh[16];
    #pragma unroll
    for (int kc = 0; kc < 16; ++kc)
        wfh[kc] = *(const short8*)(Wt + (size_t)gc * 1024 + 512 + kc * 32 + ksub);

    // --- update-phase mapping: thread -> (b, even col pair)
    const int b   = tid >> 4;
    const int hcp = (tid & 15) << 1;
    const int col = (g << 5) + hcp;
    float2 cv = *(const float2*)(c0 + (b << 9) + col);

    const int arow0 = l & 15, arow1 = (l & 15) + 16;
    const int kbyte = (l >> 4) << 4;
    const int swz0 = (arow0 & 7) << 4, swz1 = (arow1 & 7) << 4;
    const int lcw = (w << 4) + (l & 15);

    // --- stage h(0) -> Hl (IC loads; hbuf[0] from init_h)
    {
        const unsigned short* hp0 = hbuf + (w << 9) + (l << 3);
        u32x4 v0, v1, v2, v3;
        ld4x_ic(hp0, hp0 + 4096, hp0 + 8192, hp0 + 12288, v0, v1, v2, v3);
        char* hd = Hl + w * 1024 + ((l << 4) ^ (w << 4));
        *(u32x4*)hd = v0; *(u32x4*)(hd + 8192) = v1;
        *(u32x4*)(hd + 16384) = v2; *(u32x4*)(hd + 24576) = v3;
    }
    __syncthreads();

    // --- initial pre prefetch (gt=0): 4 coalesced fp16-pair dwords
    unsigned puf, pui, pug, puo;
    {
        const unsigned* pp = (const unsigned*)(pre16u + ((size_t)b << 11) + col);
        asm volatile("global_load_dword %0, %4, off\n\t"
                     "global_load_dword %1, %4, off offset:1024\n\t"
                     "global_load_dword %2, %4, off offset:2048\n\t"
                     "global_load_dword %3, %4, off offset:3072"
                     : "=&v"(puf), "=&v"(pui), "=&v"(pug), "=&v"(puo)
                     : "v"(pp) : "memory");
    }

    for (int gt = 0; gt < T_STEPS; ++gt) {
        // A. MFMA: h[32,512] @ Wh[512,16/wave] -> gates
        f32x4 acc0 = {0.f, 0.f, 0.f, 0.f}, acc1 = {0.f, 0.f, 0.f, 0.f};
        #pragma unroll
        for (int kc = 0; kc < 16; ++kc) {
            const int kb2 = kc * 64 + kbyte;
            short8 ha0 = *(const short8*)(Hl + arow0 * 1024 + (kb2 ^ swz0));
            short8 ha1 = *(const short8*)(Hl + arow1 * 1024 + (kb2 ^ swz1));
            acc0 = __builtin_amdgcn_mfma_f32_16x16x32_bf16(ha0, wfh[kc], acc0, 0, 0, 0);
            acc1 = __builtin_amdgcn_mfma_f32_16x16x32_bf16(ha1, wfh[kc], acc1, 0, 0, 0);
        }

        // B. gates -> Gl (separate region)
        #pragma unroll
        for (int ri = 0; ri < 4; ++ri) {
            const int br = ((l >> 4) << 2) + ri;
            Gl[br * GLS + lcw] = acc0[ri];
            Gl[(br + 16) * GLS + lcw] = acc1[ri];
        }
        __syncthreads();                 // (sync 1) gates visible

        // C. pre loads (issued last iter) now required
        asm volatile("s_waitcnt vmcnt(0)" ::: "memory");
        __builtin_amdgcn_sched_barrier(0);

        // D. elementwise update (fast transcendentals, fp16 pre unpack)
        const float* grow = Gl + b * GLS + hcp;
        const float2 g_f = *(const float2*)(grow);
        const float2 g_i = *(const float2*)(grow + 32);
        const float2 g_g = *(const float2*)(grow + 64);
        const float2 g_o = *(const float2*)(grow + 96);
        const float f0 = fsigm(g_f.x + h2f(puf)), f1 = fsigm(g_f.y + h2f(puf >> 16));
        const float i0 = fsigm(g_i.x + h2f(pui)), i1 = fsigm(g_i.y + h2f(pui >> 16));
        const float g0 = ftanh(g_g.x + h2f(pug)), g1 = ftanh(g_g.y + h2f(pug >> 16));
        const float o0 = fsigm(g_o.x + h2f(puo)), o1 = fsigm(g_o.y + h2f(puo >> 16));
        cv.x = f0 * cv.x + i0 * g0;
        cv.y = f1 * cv.y + i1 * g1;
        const float hn0 = o0 * ftanh(cv.x);
        const float hn1 = o1 * ftanh(cv.y);

        // E. stores: h for next step FIRST (sc1), then outs (plain)
        {
            unsigned* hdst = (unsigned*)hbuf + (((gt + 1) & 1) << 13) + (b << 8) + (col >> 1);
            const unsigned pk = pack2(hn0, hn1);
            asm volatile("global_store_dword %0, %1, off sc1" :: "v"(hdst), "v"(pk) : "memory");
            float* optr = outs + ((size_t)gt << 14) + (b << 9) + col;
            f32x2 ov; ov.x = hn0; ov.y = hn1;
            asm volatile("global_store_dwordx2 %0, %1, off" :: "v"(optr), "v"(ov) : "memory");
        }
        if (gt == T_STEPS - 1) {
            *(float2*)(hf + (b << 9) + col) = make_float2(hn0, hn1);
            *(float2*)(cf + (b << 9) + col) = make_float2(cv.x, cv.y);
            break;                              // no final barrier needed
        }

        // G. issue pre prefetch for gt+1 (after the stores)
        {
            const unsigned* pp = (const unsigned*)
                (pre16u + (((size_t)(gt + 1) << 5) + b) * 2048 + col);
            asm volatile("global_load_dword %0, %4, off\n\t"
                         "global_load_dword %1, %4, off offset:1024\n\t"
                         "global_load_dword %2, %4, off offset:2048\n\t"
                         "global_load_dword %3, %4, off offset:3072"
                         : "=&v"(puf), "=&v"(pui), "=&v"(pug), "=&v"(puo)
                         : "v"(pp) : "memory");
        }
        // H. drain ONLY the h store (oldest). outs store + 4 loads in flight.
        asm volatile("s_waitcnt vmcnt(5)" ::: "memory");

        // I. arrival: all waves' h stores drained -> tid0 publishes step done
        __syncthreads();                 // (sync 2)
        if (tid == 0)
            atomicAdd(flags + (g << 4), 1u);    // slot value = steps done

        // J. per-thread producer poll + immediate staging: thread (w,l) needs
        //    cols [l*8, l*8+8) -> producer WG l>>2 only. l>>2 spans all 16
        //    WGs across the block, so sync 3 restores full-barrier semantics.
        {
            unsigned* slot = flags + ((l >> 2) << 4);
            const unsigned tgt = (unsigned)(gt + 1);
            for (;;) {
                unsigned vb;
                asm volatile("global_load_dword %0, %1, off sc1\n\ts_waitcnt vmcnt(0)"
                             : "=v"(vb) : "v"(slot) : "memory");
                if (vb >= tgt) break;
            }
            const unsigned short* hsrc = hbuf + (((gt + 1) & 1) << 14) + (w << 9) + (l << 3);
            u32x4 v0, v1, v2, v3;
            ld4x_ic(hsrc, hsrc + 4096, hsrc + 8192, hsrc + 12288, v0, v1, v2, v3);
            char* hd = Hl + w * 1024 + ((l << 4) ^ (w << 4));
            *(u32x4*)hd = v0; *(u32x4*)(hd + 8192) = v1;
            *(u32x4*)(hd + 16384) = v2; *(u32x4*)(hd + 24576) = v3;
        }
        __syncthreads();                 // (sync 3) Hl ready
    }
}

// ---------------------------------------------------------------------------
// Minimal fallback (tiny ws): 2048 step launches, fp32, x folded in.
// ---------------------------------------------------------------------------
__global__ __launch_bounds__(256) void lstm_step(const float* __restrict__ x_t,
                                                 const float* __restrict__ h_prev,
                                                 const float* __restrict__ W,
                                                 const float* __restrict__ bias,
                                                 const float* __restrict__ c_in,
                                                 float* __restrict__ c_out,
                                                 float* __restrict__ h_out,
                                                 float* __restrict__ hf,
                                                 float* __restrict__ cf, int last) {
    const int tid = threadIdx.x;
    const int hcc = tid & 7, b = tid >> 3;
    const int col = blockIdx.x * 8 + hcc;
    float a0 = bias[col], a1 = bias[col + 512], a2 = bias[col + 1024], a3 = bias[col + 1536];
    const float* xr = x_t + (size_t)b * IN_DIM;
    const float* hr = h_prev + (size_t)b * H_DIM;
    for (int k = 0; k < IN_DIM; ++k) {
        const float v = xr[k];
        const float* wk = &W[(size_t)k * G4 + col];
        a0 += v * wk[0]; a1 += v * wk[512]; a2 += v * wk[1024]; a3 += v * wk[1536];
    }
    for (int k = 0; k < H_DIM; ++k) {
        const float v = hr[k];
        const float* wk = &W[(size_t)(512 + k) * G4 + col];
        a0 += v * wk[0]; a1 += v * wk[512]; a2 += v * wk[1024]; a3 += v * wk[1536];
    }
    const float cn = sigm(a0) * c_in[(size_t)b * H_DIM + col] + sigm(a1) * tanhf(a2);
    const float hn = sigm(a3) * tanhf(cn);
    c_out[(size_t)b * H_DIM + col] = cn;
    h_out[(size_t)b * H_DIM + col] = hn;
    if (last) { hf[(size_t)b * H_DIM + col] = hn; cf[(size_t)b * H_DIM + col] = cn; }
}

extern "C" void kernel_launch(void* const* d_in, const int* in_sizes, int n_in,
                              void* d_out, int out_size, void* d_ws, size_t ws_size,
                              hipStream_t stream) {
    const float* x    = (const float*)d_in[0];
    const float* h0   = (const float*)d_in[1];
    const float* c0   = (const float*)d_in[2];
    const float* W    = (const float*)d_in[3];
    const float* bias = (const float*)d_in[4];

    float* outs = (float*)d_out;
    float* hf   = outs + (size_t)T_STEPS * BATCH * H_DIM;
    float* cf   = hf + BATCH * H_DIM;

    // pre16 256 MiB + Wt 4 MiB + hbuf 64 KiB + flags 4 KiB = 272.7 MB
    // (< proven-available 536.9 MB)
    const size_t OFF_WT = 268435456ull;
    const size_t OFF_HB = OFF_WT + 4194304ull;
    const size_t OFF_FL = OFF_HB + 65536ull;
    const size_t NEED   = OFF_FL + 4096ull;

    if (ws_size >= NEED) {
        _Float16* pre16     = (_Float16*)d_ws;
        unsigned short* Wt  = (unsigned short*)((char*)d_ws + OFF_WT);
        unsigned short* hb  = (unsigned short*)((char*)d_ws + OFF_HB);
        unsigned int* flags = (unsigned int*)((char*)d_ws + OFF_FL);

        hipMemsetAsync(flags, 0, 4096, stream);
        wt_kernel<<<dim3(64, 32), 256, 0, stream>>>(W, Wt);
        init_h<<<64, 256, 0, stream>>>(h0, hb);
        xw_mfma<<<dim3(32, 1024), 256, 0, stream>>>(x, Wt, bias, pre16);
        lstm_scan<<<NWG, NTHR, 0, stream>>>(Wt, (const unsigned short*)pre16,
                                            c0, hb, outs, hf, cf, flags);
    } else {
        float* c_ws = (float*)d_ws;
        for (int t = 0; t < T_STEPS; ++t) {
            const float* hp = t ? outs + (size_t)(t - 1) * BATCH * H_DIM : h0;
            const float* ci = t ? c_ws : c0;
            lstm_step<<<64, 256, 0, stream>>>(x + (size_t)t * BATCH * IN_DIM,
                                              hp, W, bias, ci, c_ws,
                                              outs + (size_t)t * BATCH * H_DIM,
                                              hf, cf, (t == T_STEPS - 1) ? 1 : 0);
        }
    }
}